// Round 9
// baseline (6151.207 us; speedup 1.0000x reference)
//
#include <hip/hip_runtime.h>
#include <math.h>

#define H 51
#define LSEQ 999
#define BTOT 2048
#define E 4
#define NBLK (BTOT / E)     // 512 blocks -> 2 co-resident blocks/CU (independent barriers)

#define ROWS 256            // 64 units * 4 gates (unit-major rows: row = u*4+m)
#define K1 64               // layer1 K: k=0..50 h1, k=62 const-1 (bias), k=63 x
#define K2 128              // layer2 K: k=0..50 h1, k=62 const-1 (bias), k=64..114 h2

// ws float offsets
#define WS_W1 0
#define WS_W2 (WS_W1 + ROWS * K1)
#define WS_WL (WS_W2 + ROWS * K2)
#define WS_BL (WS_WL + 64)

// LDS frames: 1 frame = one 32-K B-fragment plane (64 lanes x 16B)
#define FRAME 1024
#define NFRAMES 16
#define PART_OFF (NFRAMES * FRAME)
#define LDS_BYTES (PART_OFF + 2 * 128 * 4)   // double-buffered partials (8 waves x 16)

// frame ids (hi plane; lo plane = +1)
#define F_L1(b, s) (((b) * 2 + (s)) * 2)       // [h1; 1; x] B-frags, double-buffered: 0..7
#define F_H2(b, s) (8 + ((b) * 2 + (s)) * 2)   // h2 B-frags, double-buffered: 8..15

typedef __attribute__((ext_vector_type(8))) short bf16x8;
typedef __attribute__((ext_vector_type(4))) float f32x4;

// ---------------- prep: padded cat-matrices, unit-major rows ----------------
// W1''[R][k]: k<51 = Whh1, k=62 = b1 (bias via const-1 slot), k=63 = Wih1
// W2''[R][k]: k<51 = Wih2 (h1 input), k=62 = b2, k=64..114 = Whh2
__global__ void prep_kernel(const float* __restrict__ Wih1, const float* __restrict__ Whh1,
                            const float* __restrict__ bih1, const float* __restrict__ bhh1,
                            const float* __restrict__ Wih2, const float* __restrict__ Whh2,
                            const float* __restrict__ bih2, const float* __restrict__ bhh2,
                            const float* __restrict__ Wlin, const float* __restrict__ blin,
                            float* __restrict__ ws) {
    int tid = threadIdx.x + blockIdx.x * blockDim.x;
    int nthr = blockDim.x * gridDim.x;
    for (int idx = tid; idx < ROWS * K1; idx += nthr) {
        int R = idx / K1, k = idx % K1;
        int u = R >> 2, m = R & 3;
        float v = 0.0f;
        if (u < H) {
            if (k < H) v = Whh1[(m * H + u) * H + k];
            else if (k == 62) v = bih1[m * H + u] + bhh1[m * H + u];
            else if (k == 63) v = Wih1[m * H + u];   // Wih1 is [204][1]
        }
        ws[WS_W1 + idx] = v;
    }
    for (int idx = tid; idx < ROWS * K2; idx += nthr) {
        int R = idx / K2, k = idx % K2;
        int u = R >> 2, m = R & 3;
        float v = 0.0f;
        if (u < H) {
            if (k < H) v = Wih2[(m * H + u) * H + k];
            else if (k == 62) v = bih2[m * H + u] + bhh2[m * H + u];
            else if (k >= 64 && k < 64 + H) v = Whh2[(m * H + u) * H + (k - 64)];
        }
        ws[WS_W2 + idx] = v;
    }
    for (int u = tid; u < 64; u += nthr) ws[WS_WL + u] = (u < H) ? Wlin[u] : 0.0f;
    if (tid == 0) ws[WS_BL] = blin[0];
}

// ---------------- helpers ----------------
__device__ __forceinline__ short f2bf(float f) {      // round-to-nearest-even
    unsigned u = __float_as_uint(f);
    unsigned r = (u + 0x7fffu + ((u >> 16) & 1u)) >> 16;
    return (short)r;
}
__device__ __forceinline__ float bf2f(short b) {
    return __uint_as_float(((unsigned)(unsigned short)b) << 16);
}
__device__ __forceinline__ float sigm(float x) {
    return __builtin_amdgcn_rcpf(1.0f + __expf(-x));
}
__device__ __forceinline__ float tanh_(float x) {
    return fmaf(-2.0f, __builtin_amdgcn_rcpf(__expf(2.0f * x) + 1.0f), 1.0f);
}
// scatter one h value into B-fragment layout: elems 0..3 <-> k=4g+j, 4..7 <-> 16+4g+j
__device__ __forceinline__ void wr_h(char* base, int fhi, int k, int e, short hi, short lo) {
    const int kk = k & 31;
    const int gg = (kk & 15) >> 2;
    const int j  = (kk & 3) + ((kk >> 4) << 2);
    const int off = (gg * 16 + e) * 16 + j * 2;
    *(short*)(base + (size_t)fhi * FRAME + off) = hi;
    *(short*)(base + (size_t)(fhi + 1) * FRAME + off) = lo;
}
__device__ __forceinline__ bf16x8 ld_fr(const char* base, int f, int l) {
    return *(const bf16x8*)(base + (size_t)f * FRAME + (size_t)l * 16);
}

// ------- main LSTM kernel: 8 waves x 2 tiles (VGPR~108), E=4, 2 blocks/CU anti-phase -------
__global__ void __launch_bounds__(512, 4)
lstm_kernel(const float* __restrict__ x, const float* __restrict__ ws,
            float* __restrict__ out) {
    __shared__ __align__(16) char smem[LDS_BYTES];

    const int tid = threadIdx.x;
    const int w = tid >> 6;        // 0..7; each wave owns 2 row-tiles T = w*2+i
    const int l = tid & 63;
    const int g = l >> 4;
    const int e = l & 15;

    for (int i = tid; i < LDS_BYTES / 4; i += 512) ((float*)smem)[i] = 0.0f;

    // ---- prologue: register-resident W fragments (hi/lo bf16 split) ----
    bf16x8 w1h[2][2], w1l[2][2], w2h[2][4], w2l[2][4];
    float wlr[2];
#pragma unroll
    for (int i = 0; i < 2; ++i) {
        const int T = w * 2 + i;
        const int rowA = T * 16 + e;
#pragma unroll
        for (int s = 0; s < 2; ++s) {
            bf16x8 hh, ll;
#pragma unroll
            for (int j = 0; j < 8; ++j) {
                const int k = s * 32 + ((j < 4) ? (4 * g + j) : (16 + 4 * g + (j - 4)));
                float wv = ws[WS_W1 + rowA * K1 + k];
                short hb = f2bf(wv);
                hh[j] = hb;
                ll[j] = f2bf(wv - bf2f(hb));
            }
            w1h[i][s] = hh; w1l[i][s] = ll;
        }
#pragma unroll
        for (int s = 0; s < 4; ++s) {
            bf16x8 hh, ll;
#pragma unroll
            for (int j = 0; j < 8; ++j) {
                const int k = s * 32 + ((j < 4) ? (4 * g + j) : (16 + 4 * g + (j - 4)));
                float wv = ws[WS_W2 + rowA * K2 + k];
                short hb = f2bf(wv);
                hh[j] = hb;
                ll[j] = f2bf(wv - bf2f(hb));
            }
            w2h[i][s] = hh; w2l[i][s] = ll;
        }
        wlr[i] = ws[WS_WL + T * 4 + g];
    }
    const float blv = ws[WS_BL];

    const int b0 = blockIdx.x * E;
    const float* xp = x + (size_t)(b0 + (l & 3)) * LSEQ;   // valid for lanes l<4
    float* pparts = (float*)(smem + PART_OFF);

    __syncthreads();   // zero-init complete

    // const-1 (bf16 1.0) at k=62 of BOTH a1 buffers (bias slot; never overwritten: u<62 guard)
    if (tid < 32) {
        const int bb = tid >> 4, ee = tid & 15;
        // k=62 -> kk=30: gg=3, j=6 -> off=(48+ee)*16+12, hi plane only (lo stays 0)
        *(short*)(smem + (size_t)F_L1(bb, 1) * FRAME + (48 + ee) * 16 + 12) = (short)0x3F80;
    }
    float xv = 0.0f;
    if (w == 0 && l < 4) {
        float x0 = xp[0];
        short hb = f2bf(x0);
        wr_h(smem, F_L1(0, 1), 63, l, hb, f2bf(x0 - bf2f(hb)));   // x(0) -> buf0 k=63
        xv = xp[1];                                               // x(1), written at phase 0
    }

    float c1s[2] = {0.f, 0.f};
    float c2s[2] = {0.f, 0.f};

    __syncthreads();   // x(0) + const-1 visible

    // Phase t: L1 computes h1(t) from a1 = [h1(t-1); 1; x(t)] (buf q=t&1);
    //          L2 computes h2(t-1), out-partials(t-1) from same a1 + h2(t-2) (F_H2 buf q).
    for (int t = 0; t <= LSEQ; ++t) {
        const int q = t & 1;

        // ---- phase-start loads ----
        bf16x8 a1h[2], a1l[2], h2h[2], h2l[2];
#pragma unroll
        for (int s = 0; s < 2; ++s) {
            a1h[s] = ld_fr(smem, F_L1(q, s), l);
            a1l[s] = ld_fr(smem, F_L1(q, s) + 1, l);
            h2h[s] = ld_fr(smem, F_H2(q, s), l);
            h2l[s] = ld_fr(smem, F_H2(q, s) + 1, l);
        }

        // out(t-2): gather partials written at phase t-1 (buffer q^1)
        if (w == 1 && l < 4 && t >= 2) {
            const float* pp = pparts + (q ^ 1) * 128;
            float r = ((pp[l] + pp[16 + l]) + (pp[32 + l] + pp[48 + l])) +
                      ((pp[64 + l] + pp[80 + l]) + (pp[96 + l] + pp[112 + l]));
            out[(size_t)(b0 + l) * LSEQ + (t - 2)] = r + blv;
        }

        // write x(t+1) into next a1 buf; prefetch x(t+2)
        float xnew = 0.0f;
        if (w == 0 && l < 4) {
            xnew = xp[(t + 2 < LSEQ) ? (t + 2) : (LSEQ - 1)];
            short hb = f2bf(xv);
            wr_h(smem, F_L1(q ^ 1, 1), 63, l, hb, f2bf(xv - bf2f(hb)));
        }

        // ---- MFMAs: 6 independent chains per lane (acc1, acc2a, acc2b x 2 tiles) ----
        f32x4 acc1[2], acc2a[2], acc2b[2];
#pragma unroll
        for (int i = 0; i < 2; ++i) {
            acc1[i]  = (f32x4){0.f, 0.f, 0.f, 0.f};
            acc2a[i] = (f32x4){0.f, 0.f, 0.f, 0.f};
            acc2b[i] = (f32x4){0.f, 0.f, 0.f, 0.f};
        }
        __builtin_amdgcn_s_setprio(1);
#pragma unroll
        for (int s = 0; s < 2; ++s)
#pragma unroll
            for (int i = 0; i < 2; ++i) {
                acc1[i]  = __builtin_amdgcn_mfma_f32_16x16x32_bf16(w1h[i][s],     a1h[s], acc1[i],  0, 0, 0);
                acc2a[i] = __builtin_amdgcn_mfma_f32_16x16x32_bf16(w2h[i][s],     a1h[s], acc2a[i], 0, 0, 0);
                acc2b[i] = __builtin_amdgcn_mfma_f32_16x16x32_bf16(w2h[i][s + 2], h2h[s], acc2b[i], 0, 0, 0);
                acc1[i]  = __builtin_amdgcn_mfma_f32_16x16x32_bf16(w1h[i][s],     a1l[s], acc1[i],  0, 0, 0);
                acc2a[i] = __builtin_amdgcn_mfma_f32_16x16x32_bf16(w2h[i][s],     a1l[s], acc2a[i], 0, 0, 0);
                acc2b[i] = __builtin_amdgcn_mfma_f32_16x16x32_bf16(w2h[i][s + 2], h2l[s], acc2b[i], 0, 0, 0);
                acc1[i]  = __builtin_amdgcn_mfma_f32_16x16x32_bf16(w1l[i][s],     a1h[s], acc1[i],  0, 0, 0);
                acc2a[i] = __builtin_amdgcn_mfma_f32_16x16x32_bf16(w2l[i][s],     a1h[s], acc2a[i], 0, 0, 0);
                acc2b[i] = __builtin_amdgcn_mfma_f32_16x16x32_bf16(w2l[i][s + 2], h2h[s], acc2b[i], 0, 0, 0);
            }
        __builtin_amdgcn_s_setprio(0);

        // ---- L1 activations -> h1(t) scatter into F_L1(q^1) ----
#pragma unroll
        for (int i = 0; i < 2; ++i) {
            float ig = sigm(acc1[i][0]), fg = sigm(acc1[i][1]);
            float gg = tanh_(acc1[i][2]), og = sigm(acc1[i][3]);
            c1s[i] = fg * c1s[i] + ig * gg;
            float h1 = og * tanh_(c1s[i]);
            short hb = f2bf(h1);
            short lb = f2bf(h1 - bf2f(hb));
            const int u = (w * 2 + i) * 4 + g;
            if (u < 62) wr_h(smem, F_L1(q ^ 1, u >> 5), u, e, hb, lb);  // 62=const,63=x slots
        }

        // ---- L2 activations (step t-1) -> h2 scatter + output partial ----
        if (t > 0) {
            float pr = 0.0f;
#pragma unroll
            for (int i = 0; i < 2; ++i) {
                f32x4 a2 = acc2a[i] + acc2b[i];
                float ig = sigm(a2[0]), fg = sigm(a2[1]);
                float gg = tanh_(a2[2]), og = sigm(a2[3]);
                c2s[i] = fg * c2s[i] + ig * gg;
                float h2 = og * tanh_(c2s[i]);
                short hb = f2bf(h2);
                short lb = f2bf(h2 - bf2f(hb));
                const int u = (w * 2 + i) * 4 + g;
                wr_h(smem, F_H2(q ^ 1, u >> 5), u, e, hb, lb);
                pr = fmaf(wlr[i], h2, pr);
            }
            pr += __shfl_xor(pr, 16);
            pr += __shfl_xor(pr, 32);
            if (l < 16) pparts[q * 128 + w * 16 + l] = pr;
        }

        __syncthreads();
        xv = xnew;
    }

    // final output: out(LSEQ-1) from partials written at phase LSEQ
    if (w == 1 && l < 4) {
        const float* pp = pparts + (LSEQ & 1) * 128;
        float r = ((pp[l] + pp[16 + l]) + (pp[32 + l] + pp[48 + l])) +
                  ((pp[64 + l] + pp[80 + l]) + (pp[96 + l] + pp[112 + l]));
        out[(size_t)(b0 + l) * LSEQ + (LSEQ - 1)] = r + blv;
    }
}

extern "C" void kernel_launch(void* const* d_in, const int* in_sizes, int n_in,
                              void* d_out, int out_size, void* d_ws, size_t ws_size,
                              hipStream_t stream) {
    const float* x    = (const float*)d_in[0];
    const float* Wih1 = (const float*)d_in[1];
    const float* Whh1 = (const float*)d_in[2];
    const float* bih1 = (const float*)d_in[3];
    const float* bhh1 = (const float*)d_in[4];
    const float* Wih2 = (const float*)d_in[5];
    const float* Whh2 = (const float*)d_in[6];
    const float* bih2 = (const float*)d_in[7];
    const float* bhh2 = (const float*)d_in[8];
    const float* Wlin = (const float*)d_in[9];
    const float* blin = (const float*)d_in[10];
    float* ws  = (float*)d_ws;
    float* out = (float*)d_out;

    hipLaunchKernelGGL(prep_kernel, dim3(64), dim3(256), 0, stream,
                       Wih1, Whh1, bih1, bhh1, Wih2, Whh2, bih2, bhh2, Wlin, blin, ws);
    hipLaunchKernelGGL(lstm_kernel, dim3(NBLK), dim3(512), 0, stream, x, ws, out);
}

// Round 10
// 2586.258 us; speedup vs baseline: 2.3784x; 2.3784x over previous
//
#include <hip/hip_runtime.h>
#include <math.h>

#define H 51
#define LSEQ 999
#define BTOT 2048
#define E 4
#define NBLK (BTOT / E)     // 512 blocks -> 2 co-resident blocks/CU (independent barriers)

#define ROWS 256            // 64 units * 4 gates (unit-major rows: row = u*4+m)
#define K1 64               // layer1 K: k=0..50 h1, k=62 const-1 (bias), k=63 x
#define K2 128              // layer2 K: k=0..50 h1, k=62 const-1 (bias), k=64..114 h2

// ws float offsets
#define WS_W1 0
#define WS_W2 (WS_W1 + ROWS * K1)
#define WS_WL (WS_W2 + ROWS * K2)
#define WS_BL (WS_WL + 64)

// LDS frames: 1 frame = one 32-K B-fragment plane (64 lanes x 16B)
#define FRAME 1024
#define NFRAMES 16
#define PART_OFF (NFRAMES * FRAME)
#define LDS_BYTES (PART_OFF + 2 * 128 * 4)   // double-buffered partials (8 waves x 16)

// frame ids (hi plane; lo plane = +1)
#define F_L1(b, s) (((b) * 2 + (s)) * 2)       // [h1; 1; x] B-frags, double-buffered: 0..7
#define F_H2(b, s) (8 + ((b) * 2 + (s)) * 2)   // h2 B-frags, double-buffered: 8..15

typedef __attribute__((ext_vector_type(8))) short bf16x8;
typedef __attribute__((ext_vector_type(4))) float f32x4;

// ---------------- prep: padded cat-matrices, unit-major rows ----------------
// W1''[R][k]: k<51 = Whh1, k=62 = b1 (bias via const-1 slot), k=63 = Wih1
// W2''[R][k]: k<51 = Wih2 (h1 input), k=62 = b2, k=64..114 = Whh2
__global__ void prep_kernel(const float* __restrict__ Wih1, const float* __restrict__ Whh1,
                            const float* __restrict__ bih1, const float* __restrict__ bhh1,
                            const float* __restrict__ Wih2, const float* __restrict__ Whh2,
                            const float* __restrict__ bih2, const float* __restrict__ bhh2,
                            const float* __restrict__ Wlin, const float* __restrict__ blin,
                            float* __restrict__ ws) {
    int tid = threadIdx.x + blockIdx.x * blockDim.x;
    int nthr = blockDim.x * gridDim.x;
    for (int idx = tid; idx < ROWS * K1; idx += nthr) {
        int R = idx / K1, k = idx % K1;
        int u = R >> 2, m = R & 3;
        float v = 0.0f;
        if (u < H) {
            if (k < H) v = Whh1[(m * H + u) * H + k];
            else if (k == 62) v = bih1[m * H + u] + bhh1[m * H + u];
            else if (k == 63) v = Wih1[m * H + u];   // Wih1 is [204][1]
        }
        ws[WS_W1 + idx] = v;
    }
    for (int idx = tid; idx < ROWS * K2; idx += nthr) {
        int R = idx / K2, k = idx % K2;
        int u = R >> 2, m = R & 3;
        float v = 0.0f;
        if (u < H) {
            if (k < H) v = Wih2[(m * H + u) * H + k];
            else if (k == 62) v = bih2[m * H + u] + bhh2[m * H + u];
            else if (k >= 64 && k < 64 + H) v = Whh2[(m * H + u) * H + (k - 64)];
        }
        ws[WS_W2 + idx] = v;
    }
    for (int u = tid; u < 64; u += nthr) ws[WS_WL + u] = (u < H) ? Wlin[u] : 0.0f;
    if (tid == 0) ws[WS_BL] = blin[0];
}

// ---------------- helpers ----------------
__device__ __forceinline__ short f2bf(float f) {      // round-to-nearest-even
    unsigned u = __float_as_uint(f);
    unsigned r = (u + 0x7fffu + ((u >> 16) & 1u)) >> 16;
    return (short)r;
}
__device__ __forceinline__ float bf2f(short b) {
    return __uint_as_float(((unsigned)(unsigned short)b) << 16);
}
__device__ __forceinline__ float sigm(float x) {
    return __builtin_amdgcn_rcpf(1.0f + __expf(-x));
}
__device__ __forceinline__ float tanh_(float x) {
    return fmaf(-2.0f, __builtin_amdgcn_rcpf(__expf(2.0f * x) + 1.0f), 1.0f);
}
// scatter one h value into B-fragment layout: elems 0..3 <-> k=4g+j, 4..7 <-> 16+4g+j
__device__ __forceinline__ void wr_h(char* base, int fhi, int k, int e, short hi, short lo) {
    const int kk = k & 31;
    const int gg = (kk & 15) >> 2;
    const int j  = (kk & 3) + ((kk >> 4) << 2);
    const int off = (gg * 16 + e) * 16 + j * 2;
    *(short*)(base + (size_t)fhi * FRAME + off) = hi;
    *(short*)(base + (size_t)(fhi + 1) * FRAME + off) = lo;
}
__device__ __forceinline__ bf16x8 ld_fr(const char* base, int f, int l) {
    return *(const bf16x8*)(base + (size_t)f * FRAME + (size_t)l * 16);
}

// ------- main LSTM kernel: 8 waves x 2 tiles (VGPR~108), E=4, 2 blocks/CU anti-phase -------
__global__ void __launch_bounds__(512, 2)
lstm_kernel(const float* __restrict__ x, const float* __restrict__ ws,
            float* __restrict__ out) {
    __shared__ __align__(16) char smem[LDS_BYTES];

    const int tid = threadIdx.x;
    const int w = tid >> 6;        // 0..7; each wave owns 2 row-tiles T = w*2+i
    const int l = tid & 63;
    const int g = l >> 4;
    const int e = l & 15;

    for (int i = tid; i < LDS_BYTES / 4; i += 512) ((float*)smem)[i] = 0.0f;

    // ---- prologue: register-resident W fragments (hi/lo bf16 split) ----
    bf16x8 w1h[2][2], w1l[2][2], w2h[2][4], w2l[2][4];
    float wlr[2];
#pragma unroll
    for (int i = 0; i < 2; ++i) {
        const int T = w * 2 + i;
        const int rowA = T * 16 + e;
#pragma unroll
        for (int s = 0; s < 2; ++s) {
            bf16x8 hh, ll;
#pragma unroll
            for (int j = 0; j < 8; ++j) {
                const int k = s * 32 + ((j < 4) ? (4 * g + j) : (16 + 4 * g + (j - 4)));
                float wv = ws[WS_W1 + rowA * K1 + k];
                short hb = f2bf(wv);
                hh[j] = hb;
                ll[j] = f2bf(wv - bf2f(hb));
            }
            w1h[i][s] = hh; w1l[i][s] = ll;
        }
#pragma unroll
        for (int s = 0; s < 4; ++s) {
            bf16x8 hh, ll;
#pragma unroll
            for (int j = 0; j < 8; ++j) {
                const int k = s * 32 + ((j < 4) ? (4 * g + j) : (16 + 4 * g + (j - 4)));
                float wv = ws[WS_W2 + rowA * K2 + k];
                short hb = f2bf(wv);
                hh[j] = hb;
                ll[j] = f2bf(wv - bf2f(hb));
            }
            w2h[i][s] = hh; w2l[i][s] = ll;
        }
        wlr[i] = ws[WS_WL + T * 4 + g];
    }
    const float blv = ws[WS_BL];

    const int b0 = blockIdx.x * E;
    const float* xp = x + (size_t)(b0 + (l & 3)) * LSEQ;   // valid for lanes l<4
    float* pparts = (float*)(smem + PART_OFF);

    __syncthreads();   // zero-init complete

    // const-1 (bf16 1.0) at k=62 of BOTH a1 buffers (bias slot; never overwritten: u<62 guard)
    if (tid < 32) {
        const int bb = tid >> 4, ee = tid & 15;
        // k=62 -> kk=30: gg=3, j=6 -> off=(48+ee)*16+12, hi plane only (lo stays 0)
        *(short*)(smem + (size_t)F_L1(bb, 1) * FRAME + (48 + ee) * 16 + 12) = (short)0x3F80;
    }
    float xv = 0.0f;
    if (w == 0 && l < 4) {
        float x0 = xp[0];
        short hb = f2bf(x0);
        wr_h(smem, F_L1(0, 1), 63, l, hb, f2bf(x0 - bf2f(hb)));   // x(0) -> buf0 k=63
        xv = xp[1];                                               // x(1), written at phase 0
    }

    float c1s[2] = {0.f, 0.f};
    float c2s[2] = {0.f, 0.f};

    __syncthreads();   // x(0) + const-1 visible

    // Phase t: L1 computes h1(t) from a1 = [h1(t-1); 1; x(t)] (buf q=t&1);
    //          L2 computes h2(t-1), out-partials(t-1) from same a1 + h2(t-2) (F_H2 buf q).
    for (int t = 0; t <= LSEQ; ++t) {
        const int q = t & 1;

        // ---- phase-start loads ----
        bf16x8 a1h[2], a1l[2], h2h[2], h2l[2];
#pragma unroll
        for (int s = 0; s < 2; ++s) {
            a1h[s] = ld_fr(smem, F_L1(q, s), l);
            a1l[s] = ld_fr(smem, F_L1(q, s) + 1, l);
            h2h[s] = ld_fr(smem, F_H2(q, s), l);
            h2l[s] = ld_fr(smem, F_H2(q, s) + 1, l);
        }

        // out(t-2): gather partials written at phase t-1 (buffer q^1)
        if (w == 1 && l < 4 && t >= 2) {
            const float* pp = pparts + (q ^ 1) * 128;
            float r = ((pp[l] + pp[16 + l]) + (pp[32 + l] + pp[48 + l])) +
                      ((pp[64 + l] + pp[80 + l]) + (pp[96 + l] + pp[112 + l]));
            out[(size_t)(b0 + l) * LSEQ + (t - 2)] = r + blv;
        }

        // write x(t+1) into next a1 buf; prefetch x(t+2)
        float xnew = 0.0f;
        if (w == 0 && l < 4) {
            xnew = xp[(t + 2 < LSEQ) ? (t + 2) : (LSEQ - 1)];
            short hb = f2bf(xv);
            wr_h(smem, F_L1(q ^ 1, 1), 63, l, hb, f2bf(xv - bf2f(hb)));
        }

        // ---- MFMAs: 6 independent chains per lane (acc1, acc2a, acc2b x 2 tiles) ----
        f32x4 acc1[2], acc2a[2], acc2b[2];
#pragma unroll
        for (int i = 0; i < 2; ++i) {
            acc1[i]  = (f32x4){0.f, 0.f, 0.f, 0.f};
            acc2a[i] = (f32x4){0.f, 0.f, 0.f, 0.f};
            acc2b[i] = (f32x4){0.f, 0.f, 0.f, 0.f};
        }
        __builtin_amdgcn_s_setprio(1);
#pragma unroll
        for (int s = 0; s < 2; ++s)
#pragma unroll
            for (int i = 0; i < 2; ++i) {
                acc1[i]  = __builtin_amdgcn_mfma_f32_16x16x32_bf16(w1h[i][s],     a1h[s], acc1[i],  0, 0, 0);
                acc2a[i] = __builtin_amdgcn_mfma_f32_16x16x32_bf16(w2h[i][s],     a1h[s], acc2a[i], 0, 0, 0);
                acc2b[i] = __builtin_amdgcn_mfma_f32_16x16x32_bf16(w2h[i][s + 2], h2h[s], acc2b[i], 0, 0, 0);
                acc1[i]  = __builtin_amdgcn_mfma_f32_16x16x32_bf16(w1h[i][s],     a1l[s], acc1[i],  0, 0, 0);
                acc2a[i] = __builtin_amdgcn_mfma_f32_16x16x32_bf16(w2h[i][s],     a1l[s], acc2a[i], 0, 0, 0);
                acc2b[i] = __builtin_amdgcn_mfma_f32_16x16x32_bf16(w2h[i][s + 2], h2l[s], acc2b[i], 0, 0, 0);
                acc1[i]  = __builtin_amdgcn_mfma_f32_16x16x32_bf16(w1l[i][s],     a1h[s], acc1[i],  0, 0, 0);
                acc2a[i] = __builtin_amdgcn_mfma_f32_16x16x32_bf16(w2l[i][s],     a1h[s], acc2a[i], 0, 0, 0);
                acc2b[i] = __builtin_amdgcn_mfma_f32_16x16x32_bf16(w2l[i][s + 2], h2h[s], acc2b[i], 0, 0, 0);
            }
        __builtin_amdgcn_s_setprio(0);

        // ---- L1 activations -> h1(t) scatter into F_L1(q^1) ----
#pragma unroll
        for (int i = 0; i < 2; ++i) {
            float ig = sigm(acc1[i][0]), fg = sigm(acc1[i][1]);
            float gg = tanh_(acc1[i][2]), og = sigm(acc1[i][3]);
            c1s[i] = fg * c1s[i] + ig * gg;
            float h1 = og * tanh_(c1s[i]);
            short hb = f2bf(h1);
            short lb = f2bf(h1 - bf2f(hb));
            const int u = (w * 2 + i) * 4 + g;
            if (u < 62) wr_h(smem, F_L1(q ^ 1, u >> 5), u, e, hb, lb);  // 62=const,63=x slots
        }

        // ---- L2 activations (step t-1) -> h2 scatter + output partial ----
        if (t > 0) {
            float pr = 0.0f;
#pragma unroll
            for (int i = 0; i < 2; ++i) {
                f32x4 a2 = acc2a[i] + acc2b[i];
                float ig = sigm(a2[0]), fg = sigm(a2[1]);
                float gg = tanh_(a2[2]), og = sigm(a2[3]);
                c2s[i] = fg * c2s[i] + ig * gg;
                float h2 = og * tanh_(c2s[i]);
                short hb = f2bf(h2);
                short lb = f2bf(h2 - bf2f(hb));
                const int u = (w * 2 + i) * 4 + g;
                wr_h(smem, F_H2(q ^ 1, u >> 5), u, e, hb, lb);
                pr = fmaf(wlr[i], h2, pr);
            }
            pr += __shfl_xor(pr, 16);
            pr += __shfl_xor(pr, 32);
            if (l < 16) pparts[q * 128 + w * 16 + l] = pr;
        }

        __syncthreads();
        xv = xnew;
    }

    // final output: out(LSEQ-1) from partials written at phase LSEQ
    if (w == 1 && l < 4) {
        const float* pp = pparts + (LSEQ & 1) * 128;
        float r = ((pp[l] + pp[16 + l]) + (pp[32 + l] + pp[48 + l])) +
                  ((pp[64 + l] + pp[80 + l]) + (pp[96 + l] + pp[112 + l]));
        out[(size_t)(b0 + l) * LSEQ + (LSEQ - 1)] = r + blv;
    }
}

extern "C" void kernel_launch(void* const* d_in, const int* in_sizes, int n_in,
                              void* d_out, int out_size, void* d_ws, size_t ws_size,
                              hipStream_t stream) {
    const float* x    = (const float*)d_in[0];
    const float* Wih1 = (const float*)d_in[1];
    const float* Whh1 = (const float*)d_in[2];
    const float* bih1 = (const float*)d_in[3];
    const float* bhh1 = (const float*)d_in[4];
    const float* Wih2 = (const float*)d_in[5];
    const float* Whh2 = (const float*)d_in[6];
    const float* bih2 = (const float*)d_in[7];
    const float* bhh2 = (const float*)d_in[8];
    const float* Wlin = (const float*)d_in[9];
    const float* blin = (const float*)d_in[10];
    float* ws  = (float*)d_ws;
    float* out = (float*)d_out;

    hipLaunchKernelGGL(prep_kernel, dim3(64), dim3(256), 0, stream,
                       Wih1, Whh1, bih1, bhh1, Wih2, Whh2, bih2, bhh2, Wlin, blin, ws);
    hipLaunchKernelGGL(lstm_kernel, dim3(NBLK), dim3(512), 0, stream, x, ws, out);
}

// Round 11
// 2046.879 us; speedup vs baseline: 3.0052x; 1.2635x over previous
//
#include <hip/hip_runtime.h>
#include <math.h>

#define H 51
#define LSEQ 999
#define BTOT 2048
#define EBLK 32             // 2 groups x 16 elems per block
#define NBLK (BTOT / EBLK)  // 64 blocks, all resident

#define ROWS 256            // 64 units * 4 gates (unit-major rows: row = u*4+m)
#define K1 64               // layer1 K: k=0..50 h1, k=62 const-1 (bias), k=63 x
#define K2 128              // layer2 K: k=0..50 h1, k=62 const-1 (bias), k=64..114 h2

// ws float offsets
#define WS_W1 0
#define WS_W2 (WS_W1 + ROWS * K1)
#define WS_WL (WS_W2 + ROWS * K2)
#define WS_BL (WS_WL + 64)

// LDS frames: 1 frame = one 32-K B-fragment plane (64 lanes x 16B), single (hi) plane only
#define FRAME 1024
#define NFRAMES 16
#define PART_OFF (NFRAMES * FRAME)
#define LDS_BYTES (PART_OFF + 2 * 2 * 128 * 4)   // [group][buf][128] partials

// frame ids: per group g (0/1): a1 frags then h2 frags, each double-buffered
#define F_A1(g, b, s) ((g) * 8 + (b) * 2 + (s))        // [h1; 1; x] frags
#define F_H2G(g, b, s) ((g) * 8 + 4 + (b) * 2 + (s))   // h2 frags

typedef __attribute__((ext_vector_type(8))) short bf16x8;
typedef __attribute__((ext_vector_type(4))) float f32x4;

// ---------------- prep: padded cat-matrices, unit-major rows ----------------
// W1''[R][k]: k<51 = Whh1, k=62 = b1 (bias via const-1 slot), k=63 = Wih1
// W2''[R][k]: k<51 = Wih2 (h1 input), k=62 = b2, k=64..114 = Whh2
__global__ void prep_kernel(const float* __restrict__ Wih1, const float* __restrict__ Whh1,
                            const float* __restrict__ bih1, const float* __restrict__ bhh1,
                            const float* __restrict__ Wih2, const float* __restrict__ Whh2,
                            const float* __restrict__ bih2, const float* __restrict__ bhh2,
                            const float* __restrict__ Wlin, const float* __restrict__ blin,
                            float* __restrict__ ws) {
    int tid = threadIdx.x + blockIdx.x * blockDim.x;
    int nthr = blockDim.x * gridDim.x;
    for (int idx = tid; idx < ROWS * K1; idx += nthr) {
        int R = idx / K1, k = idx % K1;
        int u = R >> 2, m = R & 3;
        float v = 0.0f;
        if (u < H) {
            if (k < H) v = Whh1[(m * H + u) * H + k];
            else if (k == 62) v = bih1[m * H + u] + bhh1[m * H + u];
            else if (k == 63) v = Wih1[m * H + u];   // Wih1 is [204][1]
        }
        ws[WS_W1 + idx] = v;
    }
    for (int idx = tid; idx < ROWS * K2; idx += nthr) {
        int R = idx / K2, k = idx % K2;
        int u = R >> 2, m = R & 3;
        float v = 0.0f;
        if (u < H) {
            if (k < H) v = Wih2[(m * H + u) * H + k];
            else if (k == 62) v = bih2[m * H + u] + bhh2[m * H + u];
            else if (k >= 64 && k < 64 + H) v = Whh2[(m * H + u) * H + (k - 64)];
        }
        ws[WS_W2 + idx] = v;
    }
    for (int u = tid; u < 64; u += nthr) ws[WS_WL + u] = (u < H) ? Wlin[u] : 0.0f;
    if (tid == 0) ws[WS_BL] = blin[0];
}

// ---------------- helpers ----------------
__device__ __forceinline__ short f2bf(float f) {      // round-to-nearest-even
    unsigned u = __float_as_uint(f);
    unsigned r = (u + 0x7fffu + ((u >> 16) & 1u)) >> 16;
    return (short)r;
}
__device__ __forceinline__ float bf2f(short b) {
    return __uint_as_float(((unsigned)(unsigned short)b) << 16);
}
__device__ __forceinline__ float sigm(float x) {
    return __builtin_amdgcn_rcpf(1.0f + __expf(-x));
}
__device__ __forceinline__ float tanh_(float x) {
    return fmaf(-2.0f, __builtin_amdgcn_rcpf(__expf(2.0f * x) + 1.0f), 1.0f);
}
// scatter one bf16 h value into B-fragment layout: elems 0..3 <-> k=4g+j, 4..7 <-> 16+4g+j
__device__ __forceinline__ void wr1(char* base, int f, int k, int e, short hi) {
    const int kk = k & 31;
    const int gg = (kk & 15) >> 2;
    const int j  = (kk & 3) + ((kk >> 4) << 2);
    const int off = (gg * 16 + e) * 16 + j * 2;
    *(short*)(base + (size_t)f * FRAME + off) = hi;
}
__device__ __forceinline__ bf16x8 ld_fr(const char* base, int f, int l) {
    return *(const bf16x8*)(base + (size_t)f * FRAME + (size_t)l * 16);
}

// ---- main kernel: 8 waves x 2 row-tiles, 2 element groups (static ILP), h hi-only ----
__global__ void __launch_bounds__(512, 2)
lstm_kernel(const float* __restrict__ x, const float* __restrict__ ws,
            float* __restrict__ out) {
    __shared__ __align__(16) char smem[LDS_BYTES];

    const int tid = threadIdx.x;
    const int w = tid >> 6;        // 0..7; each wave owns 2 row-tiles T = w*2+i
    const int l = tid & 63;
    const int g = l >> 4;
    const int e = l & 15;

    for (int i = tid; i < LDS_BYTES / 4; i += 512) ((float*)smem)[i] = 0.0f;

    // ---- prologue: register-resident W fragments (hi/lo bf16 split; weights stay exact) ----
    bf16x8 w1h[2][2], w1l[2][2], w2h[2][4], w2l[2][4];
    float wlr[2];
#pragma unroll
    for (int i = 0; i < 2; ++i) {
        const int T = w * 2 + i;
        const int rowA = T * 16 + e;
#pragma unroll
        for (int s = 0; s < 2; ++s) {
            bf16x8 hh, ll;
#pragma unroll
            for (int j = 0; j < 8; ++j) {
                const int k = s * 32 + ((j < 4) ? (4 * g + j) : (16 + 4 * g + (j - 4)));
                float wv = ws[WS_W1 + rowA * K1 + k];
                short hb = f2bf(wv);
                hh[j] = hb;
                ll[j] = f2bf(wv - bf2f(hb));
            }
            w1h[i][s] = hh; w1l[i][s] = ll;
        }
#pragma unroll
        for (int s = 0; s < 4; ++s) {
            bf16x8 hh, ll;
#pragma unroll
            for (int j = 0; j < 8; ++j) {
                const int k = s * 32 + ((j < 4) ? (4 * g + j) : (16 + 4 * g + (j - 4)));
                float wv = ws[WS_W2 + rowA * K2 + k];
                short hb = f2bf(wv);
                hh[j] = hb;
                ll[j] = f2bf(wv - bf2f(hb));
            }
            w2h[i][s] = hh; w2l[i][s] = ll;
        }
        wlr[i] = ws[WS_WL + T * 4 + g];
    }
    const float blv = ws[WS_BL];

    const int b0 = blockIdx.x * EBLK;
    // x staging: waves 0 (group A) and 4 (group B), lanes 0..15
    const int xgrp = (w >> 2) & 1;
    const float* xp = x + (size_t)(b0 + xgrp * 16 + e) * LSEQ;
    float* pparts = (float*)(smem + PART_OFF);

    __syncthreads();   // zero-init complete

    // const-1 (bf16 1.0) at k=62 of both a1 buffers of both groups (bias slot)
    if (tid < 64) {
        const int gg_ = tid >> 5, bb = (tid >> 4) & 1, ee = tid & 15;
        // k=62 -> kk=30: gg=3, j=6 -> off=(48+ee)*16+12
        *(short*)(smem + (size_t)F_A1(gg_, bb, 1) * FRAME + (48 + ee) * 16 + 12) = (short)0x3F80;
    }
    float xv = 0.0f;
    if ((w & 3) == 0 && l < 16) {
        float x0 = xp[0];
        wr1(smem, F_A1(xgrp, 0, 1), 63, e, f2bf(x0));   // x(0) -> buf0 k=63
        xv = xp[1];                                      // x(1), written at phase 0
    }

    float c1s[2][2] = {{0.f, 0.f}, {0.f, 0.f}};   // [group][tile]
    float c2s[2][2] = {{0.f, 0.f}, {0.f, 0.f}};

    __syncthreads();   // x(0) + const-1 visible

    // Phase t: per group: L1 computes h1(t) from a1=[h1(t-1);1;x(t)] (buf q);
    //          L2 computes h2(t-1), out-partials(t-1) from same a1 + h2(t-2).
    for (int t = 0; t <= LSEQ; ++t) {
        const int q = t & 1;

        // ---- phase-start loads: 4 frags per group ----
        bf16x8 a1f[2][2], h2f[2][2];
#pragma unroll
        for (int gp = 0; gp < 2; ++gp)
#pragma unroll
            for (int s = 0; s < 2; ++s) {
                a1f[gp][s] = ld_fr(smem, F_A1(gp, q, s), l);
                h2f[gp][s] = ld_fr(smem, F_H2G(gp, q, s), l);
            }

        // out(t-2): waves 1 (A) and 5 (B) gather partials written at phase t-1
        if ((w & 3) == 1 && l < 16 && t >= 2) {
            const int ogrp = (w >> 2) & 1;
            const float* pp = pparts + ogrp * 256 + (q ^ 1) * 128;
            float r = ((pp[l] + pp[16 + l]) + (pp[32 + l] + pp[48 + l])) +
                      ((pp[64 + l] + pp[80 + l]) + (pp[96 + l] + pp[112 + l]));
            out[(size_t)(b0 + ogrp * 16 + l) * LSEQ + (t - 2)] = r + blv;
        }

        // write x(t+1) into next a1 buf; prefetch x(t+2)
        float xnew = 0.0f;
        if ((w & 3) == 0 && l < 16) {
            xnew = xp[(t + 2 < LSEQ) ? (t + 2) : (LSEQ - 1)];
            wr1(smem, F_A1(xgrp, q ^ 1, 1), 63, e, f2bf(xv));
        }

        // ---- MFMAs: 48 per wave, 12 independent 4-deep chains (2 groups x 6 accs) ----
        f32x4 acc1[2][2], acc2a[2][2], acc2b[2][2];
#pragma unroll
        for (int gp = 0; gp < 2; ++gp)
#pragma unroll
            for (int i = 0; i < 2; ++i) {
                acc1[gp][i]  = (f32x4){0.f, 0.f, 0.f, 0.f};
                acc2a[gp][i] = (f32x4){0.f, 0.f, 0.f, 0.f};
                acc2b[gp][i] = (f32x4){0.f, 0.f, 0.f, 0.f};
            }
        __builtin_amdgcn_s_setprio(1);
#pragma unroll
        for (int s = 0; s < 2; ++s)
#pragma unroll
            for (int i = 0; i < 2; ++i)
#pragma unroll
                for (int gp = 0; gp < 2; ++gp) {
                    acc1[gp][i]  = __builtin_amdgcn_mfma_f32_16x16x32_bf16(w1h[i][s],     a1f[gp][s], acc1[gp][i],  0, 0, 0);
                    acc2a[gp][i] = __builtin_amdgcn_mfma_f32_16x16x32_bf16(w2h[i][s],     a1f[gp][s], acc2a[gp][i], 0, 0, 0);
                    acc2b[gp][i] = __builtin_amdgcn_mfma_f32_16x16x32_bf16(w2h[i][s + 2], h2f[gp][s], acc2b[gp][i], 0, 0, 0);
                    acc1[gp][i]  = __builtin_amdgcn_mfma_f32_16x16x32_bf16(w1l[i][s],     a1f[gp][s], acc1[gp][i],  0, 0, 0);
                    acc2a[gp][i] = __builtin_amdgcn_mfma_f32_16x16x32_bf16(w2l[i][s],     a1f[gp][s], acc2a[gp][i], 0, 0, 0);
                    acc2b[gp][i] = __builtin_amdgcn_mfma_f32_16x16x32_bf16(w2l[i][s + 2], h2f[gp][s], acc2b[gp][i], 0, 0, 0);
                }
        __builtin_amdgcn_s_setprio(0);

        // ---- L1 activations -> h1(t) scatter (hi plane only) ----
#pragma unroll
        for (int gp = 0; gp < 2; ++gp)
#pragma unroll
            for (int i = 0; i < 2; ++i) {
                float ig = sigm(acc1[gp][i][0]), fg = sigm(acc1[gp][i][1]);
                float gg_ = tanh_(acc1[gp][i][2]), og = sigm(acc1[gp][i][3]);
                c1s[gp][i] = fg * c1s[gp][i] + ig * gg_;
                float h1 = og * tanh_(c1s[gp][i]);
                const int u = (w * 2 + i) * 4 + g;
                if (u < 62) wr1(smem, F_A1(gp, q ^ 1, u >> 5), u, e, f2bf(h1));
            }

        // ---- L2 activations (step t-1) -> h2 scatter + output partials ----
        if (t > 0) {
            float pr[2] = {0.f, 0.f};
#pragma unroll
            for (int gp = 0; gp < 2; ++gp)
#pragma unroll
                for (int i = 0; i < 2; ++i) {
                    f32x4 a2 = acc2a[gp][i] + acc2b[gp][i];
                    float ig = sigm(a2[0]), fg = sigm(a2[1]);
                    float gg_ = tanh_(a2[2]), og = sigm(a2[3]);
                    c2s[gp][i] = fg * c2s[gp][i] + ig * gg_;
                    float h2 = og * tanh_(c2s[gp][i]);
                    const int u = (w * 2 + i) * 4 + g;
                    wr1(smem, F_H2G(gp, q ^ 1, u >> 5), u, e, f2bf(h2));
                    pr[gp] = fmaf(wlr[i], h2, pr[gp]);
                }
#pragma unroll
            for (int gp = 0; gp < 2; ++gp) {
                pr[gp] += __shfl_xor(pr[gp], 16);
                pr[gp] += __shfl_xor(pr[gp], 32);
                if (l < 16) pparts[gp * 256 + q * 128 + w * 16 + l] = pr[gp];
            }
        }

        __syncthreads();
        xv = xnew;
    }

    // final output: out(LSEQ-1) from partials written at phase LSEQ
    if ((w & 3) == 1 && l < 16) {
        const int ogrp = (w >> 2) & 1;
        const float* pp = pparts + ogrp * 256 + (LSEQ & 1) * 128;
        float r = ((pp[l] + pp[16 + l]) + (pp[32 + l] + pp[48 + l])) +
                  ((pp[64 + l] + pp[80 + l]) + (pp[96 + l] + pp[112 + l]));
        out[(size_t)(b0 + ogrp * 16 + l) * LSEQ + (LSEQ - 1)] = r + blv;
    }
}

extern "C" void kernel_launch(void* const* d_in, const int* in_sizes, int n_in,
                              void* d_out, int out_size, void* d_ws, size_t ws_size,
                              hipStream_t stream) {
    const float* x    = (const float*)d_in[0];
    const float* Wih1 = (const float*)d_in[1];
    const float* Whh1 = (const float*)d_in[2];
    const float* bih1 = (const float*)d_in[3];
    const float* bhh1 = (const float*)d_in[4];
    const float* Wih2 = (const float*)d_in[5];
    const float* Whh2 = (const float*)d_in[6];
    const float* bih2 = (const float*)d_in[7];
    const float* bhh2 = (const float*)d_in[8];
    const float* Wlin = (const float*)d_in[9];
    const float* blin = (const float*)d_in[10];
    float* ws  = (float*)d_ws;
    float* out = (float*)d_out;

    hipLaunchKernelGGL(prep_kernel, dim3(64), dim3(256), 0, stream,
                       Wih1, Whh1, bih1, bhh1, Wih2, Whh2, bih2, bhh2, Wlin, blin, ws);
    hipLaunchKernelGGL(lstm_kernel, dim3(NBLK), dim3(512), 0, stream, x, ws, out);
}

// Round 12
// 1003.003 us; speedup vs baseline: 6.1328x; 2.0408x over previous
//
#include <hip/hip_runtime.h>
#include <math.h>

#define H 51
#define LSEQ 999
#define BTOT 2048
#define E 16
#define NBLK (BTOT / E)     // 128 blocks

#define ROWS 256            // 64 units * 4 gates (unit-major rows: row = u*4+m)
#define K1 64               // layer1 K: k=0..50 h1, k=62 const-1 (bias), k=63 x
#define K2 128              // layer2 K: k=0..50 h1, k=62 const-1 (bias), k=64..114 h2

// ws float offsets
#define WS_W1 0
#define WS_W2 (WS_W1 + ROWS * K1)
#define WS_WL (WS_W2 + ROWS * K2)
#define WS_BL (WS_WL + 64)

// LDS frames: 1 frame = one 32-K B-fragment plane (64 lanes x 16B); h is bf16 hi-only
#define FRAME 1024
#define NFRAMES 8
#define PART_OFF (NFRAMES * FRAME)
#define LDS_BYTES (PART_OFF + 2 * 128 * 4)   // double-buffered partials (8 waves x 16)

#define F_L1(b, s) ((b) * 2 + (s))        // [h1; 1; x] B-frags, double-buffered: 0..3
#define F_H2(b, s) (4 + (b) * 2 + (s))    // h2 B-frags, double-buffered: 4..7

typedef __attribute__((ext_vector_type(8))) short bf16x8;
typedef __attribute__((ext_vector_type(4))) float f32x4;

// ---------------- prep: padded cat-matrices, unit-major rows ----------------
// W1''[R][k]: k<51 = Whh1, k=62 = b1 (bias via const-1 slot), k=63 = Wih1
// W2''[R][k]: k<51 = Wih2 (h1 input), k=62 = b2, k=64..114 = Whh2
__global__ void prep_kernel(const float* __restrict__ Wih1, const float* __restrict__ Whh1,
                            const float* __restrict__ bih1, const float* __restrict__ bhh1,
                            const float* __restrict__ Wih2, const float* __restrict__ Whh2,
                            const float* __restrict__ bih2, const float* __restrict__ bhh2,
                            const float* __restrict__ Wlin, const float* __restrict__ blin,
                            float* __restrict__ ws) {
    int tid = threadIdx.x + blockIdx.x * blockDim.x;
    int nthr = blockDim.x * gridDim.x;
    for (int idx = tid; idx < ROWS * K1; idx += nthr) {
        int R = idx / K1, k = idx % K1;
        int u = R >> 2, m = R & 3;
        float v = 0.0f;
        if (u < H) {
            if (k < H) v = Whh1[(m * H + u) * H + k];
            else if (k == 62) v = bih1[m * H + u] + bhh1[m * H + u];
            else if (k == 63) v = Wih1[m * H + u];   // Wih1 is [204][1]
        }
        ws[WS_W1 + idx] = v;
    }
    for (int idx = tid; idx < ROWS * K2; idx += nthr) {
        int R = idx / K2, k = idx % K2;
        int u = R >> 2, m = R & 3;
        float v = 0.0f;
        if (u < H) {
            if (k < H) v = Wih2[(m * H + u) * H + k];
            else if (k == 62) v = bih2[m * H + u] + bhh2[m * H + u];
            else if (k >= 64 && k < 64 + H) v = Whh2[(m * H + u) * H + (k - 64)];
        }
        ws[WS_W2 + idx] = v;
    }
    for (int u = tid; u < 64; u += nthr) ws[WS_WL + u] = (u < H) ? Wlin[u] : 0.0f;
    if (tid == 0) ws[WS_BL] = blin[0];
}

// ---------------- helpers ----------------
__device__ __forceinline__ short f2bf(float f) {      // round-to-nearest-even
    unsigned u = __float_as_uint(f);
    unsigned r = (u + 0x7fffu + ((u >> 16) & 1u)) >> 16;
    return (short)r;
}
__device__ __forceinline__ float bf2f(short b) {
    return __uint_as_float(((unsigned)(unsigned short)b) << 16);
}
__device__ __forceinline__ float sigm(float x) {
    return __builtin_amdgcn_rcpf(1.0f + __expf(-x));
}
__device__ __forceinline__ float tanh_(float x) {
    return fmaf(-2.0f, __builtin_amdgcn_rcpf(__expf(2.0f * x) + 1.0f), 1.0f);
}
// scatter one bf16 h value into B-fragment layout: elems 0..3 <-> k=4g+j, 4..7 <-> 16+4g+j
__device__ __forceinline__ void wr1(char* base, int f, int k, int e, short hi) {
    const int kk = k & 31;
    const int gg = (kk & 15) >> 2;
    const int j  = (kk & 3) + ((kk >> 4) << 2);
    const int off = (gg * 16 + e) * 16 + j * 2;
    *(short*)(base + (size_t)f * FRAME + off) = hi;
}
__device__ __forceinline__ bf16x8 ld_fr(const char* base, int f, int l) {
    return *(const bf16x8*)(base + (size_t)f * FRAME + (size_t)l * 16);
}

// ------- main kernel: 8 waves x 2 row-tiles, E=16, h hi-only, 1-barrier skewed phase -------
__global__ void __launch_bounds__(512, 1)
lstm_kernel(const float* __restrict__ x, const float* __restrict__ ws,
            float* __restrict__ out) {
    __shared__ __align__(16) char smem[LDS_BYTES];

    const int tid = threadIdx.x;
    const int w = tid >> 6;        // 0..7; each wave owns 2 row-tiles T = w*2+i
    const int l = tid & 63;
    const int g = l >> 4;
    const int e = l & 15;

    for (int i = tid; i < LDS_BYTES / 4; i += 512) ((float*)smem)[i] = 0.0f;

    // ---- prologue: register-resident W fragments (hi/lo bf16 split; weights exact) ----
    bf16x8 w1h[2][2], w1l[2][2], w2h[2][4], w2l[2][4];
    float wlr[2];
#pragma unroll
    for (int i = 0; i < 2; ++i) {
        const int T = w * 2 + i;
        const int rowA = T * 16 + e;
#pragma unroll
        for (int s = 0; s < 2; ++s) {
            bf16x8 hh, ll;
#pragma unroll
            for (int j = 0; j < 8; ++j) {
                const int k = s * 32 + ((j < 4) ? (4 * g + j) : (16 + 4 * g + (j - 4)));
                float wv = ws[WS_W1 + rowA * K1 + k];
                short hb = f2bf(wv);
                hh[j] = hb;
                ll[j] = f2bf(wv - bf2f(hb));
            }
            w1h[i][s] = hh; w1l[i][s] = ll;
        }
#pragma unroll
        for (int s = 0; s < 4; ++s) {
            bf16x8 hh, ll;
#pragma unroll
            for (int j = 0; j < 8; ++j) {
                const int k = s * 32 + ((j < 4) ? (4 * g + j) : (16 + 4 * g + (j - 4)));
                float wv = ws[WS_W2 + rowA * K2 + k];
                short hb = f2bf(wv);
                hh[j] = hb;
                ll[j] = f2bf(wv - bf2f(hb));
            }
            w2h[i][s] = hh; w2l[i][s] = ll;
        }
        wlr[i] = ws[WS_WL + T * 4 + g];
    }
    const float blv = ws[WS_BL];

    const int b0 = blockIdx.x * E;
    const float* xp = x + (size_t)(b0 + e) * LSEQ;   // used by wave0 lanes<16 only
    float* pparts = (float*)(smem + PART_OFF);

    __syncthreads();   // zero-init complete

    // const-1 (bf16 1.0) at k=62 of both a1 buffers (bias slot; u<62 guard protects it)
    if (tid < 32) {
        const int bb = tid >> 4, ee = tid & 15;
        // k=62 -> kk=30: gg=3, j=6 -> off=(48+ee)*16+12
        *(short*)(smem + (size_t)F_L1(bb, 1) * FRAME + (48 + ee) * 16 + 12) = (short)0x3F80;
    }
    float xv = 0.0f;
    if (w == 0 && l < 16) {
        float x0 = xp[0];
        wr1(smem, F_L1(0, 1), 63, e, f2bf(x0));   // x(0) -> buf0 k=63
        xv = xp[1];                                // x(1), written at phase 0
    }

    float c1s[2] = {0.f, 0.f};
    float c2s[2] = {0.f, 0.f};

    __syncthreads();   // x(0) + const-1 visible

    // Phase t: L1 computes h1(t) from a1 = [h1(t-1); 1; x(t)] (buf q=t&1);
    //          L2 computes h2(t-1), out-partials(t-1) from same a1 + h2(t-2) (F_H2 buf q).
    for (int t = 0; t <= LSEQ; ++t) {
        const int q = t & 1;

        // ---- phase-start loads: 4 b128 per lane ----
        bf16x8 a1f[2], h2f[2];
#pragma unroll
        for (int s = 0; s < 2; ++s) {
            a1f[s] = ld_fr(smem, F_L1(q, s), l);
            h2f[s] = ld_fr(smem, F_H2(q, s), l);
        }

        // out(t-2): gather partials written at phase t-1 (buffer q^1)
        if (w == 1 && l < 16 && t >= 2) {
            const float* pp = pparts + (q ^ 1) * 128;
            float r = ((pp[l] + pp[16 + l]) + (pp[32 + l] + pp[48 + l])) +
                      ((pp[64 + l] + pp[80 + l]) + (pp[96 + l] + pp[112 + l]));
            out[(size_t)(b0 + l) * LSEQ + (t - 2)] = r + blv;
        }

        // write x(t+1) into next a1 buf; prefetch x(t+2)
        float xnew = 0.0f;
        if (w == 0 && l < 16) {
            xnew = xp[(t + 2 < LSEQ) ? (t + 2) : (LSEQ - 1)];
            wr1(smem, F_L1(q ^ 1, 1), 63, e, f2bf(xv));
        }

        // ---- MFMAs: 24 per wave, 6 independent 4-deep chains ----
        f32x4 acc1[2], acc2a[2], acc2b[2];
#pragma unroll
        for (int i = 0; i < 2; ++i) {
            acc1[i]  = (f32x4){0.f, 0.f, 0.f, 0.f};
            acc2a[i] = (f32x4){0.f, 0.f, 0.f, 0.f};
            acc2b[i] = (f32x4){0.f, 0.f, 0.f, 0.f};
        }
        __builtin_amdgcn_s_setprio(1);
#pragma unroll
        for (int s = 0; s < 2; ++s)
#pragma unroll
            for (int i = 0; i < 2; ++i) {
                acc1[i]  = __builtin_amdgcn_mfma_f32_16x16x32_bf16(w1h[i][s],     a1f[s], acc1[i],  0, 0, 0);
                acc2a[i] = __builtin_amdgcn_mfma_f32_16x16x32_bf16(w2h[i][s],     a1f[s], acc2a[i], 0, 0, 0);
                acc2b[i] = __builtin_amdgcn_mfma_f32_16x16x32_bf16(w2h[i][s + 2], h2f[s], acc2b[i], 0, 0, 0);
                acc1[i]  = __builtin_amdgcn_mfma_f32_16x16x32_bf16(w1l[i][s],     a1f[s], acc1[i],  0, 0, 0);
                acc2a[i] = __builtin_amdgcn_mfma_f32_16x16x32_bf16(w2l[i][s],     a1f[s], acc2a[i], 0, 0, 0);
                acc2b[i] = __builtin_amdgcn_mfma_f32_16x16x32_bf16(w2l[i][s + 2], h2f[s], acc2b[i], 0, 0, 0);
            }
        __builtin_amdgcn_s_setprio(0);

        // ---- L1 activations -> h1(t) scatter into F_L1(q^1) (hi plane only) ----
#pragma unroll
        for (int i = 0; i < 2; ++i) {
            float ig = sigm(acc1[i][0]), fg = sigm(acc1[i][1]);
            float gg = tanh_(acc1[i][2]), og = sigm(acc1[i][3]);
            c1s[i] = fg * c1s[i] + ig * gg;
            float h1 = og * tanh_(c1s[i]);
            const int u = (w * 2 + i) * 4 + g;
            if (u < 62) wr1(smem, F_L1(q ^ 1, u >> 5), u, e, f2bf(h1));  // 62=const,63=x
        }

        // ---- L2 activations (step t-1) -> h2 scatter + output partial ----
        if (t > 0) {
            float pr = 0.0f;
#pragma unroll
            for (int i = 0; i < 2; ++i) {
                f32x4 a2 = acc2a[i] + acc2b[i];
                float ig = sigm(a2[0]), fg = sigm(a2[1]);
                float gg = tanh_(a2[2]), og = sigm(a2[3]);
                c2s[i] = fg * c2s[i] + ig * gg;
                float h2 = og * tanh_(c2s[i]);
                const int u = (w * 2 + i) * 4 + g;
                wr1(smem, F_H2(q ^ 1, u >> 5), u, e, f2bf(h2));
                pr = fmaf(wlr[i], h2, pr);
            }
            pr += __shfl_xor(pr, 16);
            pr += __shfl_xor(pr, 32);
            if (l < 16) pparts[q * 128 + w * 16 + l] = pr;
        }

        __syncthreads();
        xv = xnew;
    }

    // final output: out(LSEQ-1) from partials written at phase LSEQ
    if (w == 1 && l < 16) {
        const float* pp = pparts + (LSEQ & 1) * 128;
        float r = ((pp[l] + pp[16 + l]) + (pp[32 + l] + pp[48 + l])) +
                  ((pp[64 + l] + pp[80 + l]) + (pp[96 + l] + pp[112 + l]));
        out[(size_t)(b0 + l) * LSEQ + (LSEQ - 1)] = r + blv;
    }
}

extern "C" void kernel_launch(void* const* d_in, const int* in_sizes, int n_in,
                              void* d_out, int out_size, void* d_ws, size_t ws_size,
                              hipStream_t stream) {
    const float* x    = (const float*)d_in[0];
    const float* Wih1 = (const float*)d_in[1];
    const float* Whh1 = (const float*)d_in[2];
    const float* bih1 = (const float*)d_in[3];
    const float* bhh1 = (const float*)d_in[4];
    const float* Wih2 = (const float*)d_in[5];
    const float* Whh2 = (const float*)d_in[6];
    const float* bih2 = (const float*)d_in[7];
    const float* bhh2 = (const float*)d_in[8];
    const float* Wlin = (const float*)d_in[9];
    const float* blin = (const float*)d_in[10];
    float* ws  = (float*)d_ws;
    float* out = (float*)d_out;

    hipLaunchKernelGGL(prep_kernel, dim3(64), dim3(256), 0, stream,
                       Wih1, Whh1, bih1, bhh1, Wih2, Whh2, bih2, bhh2, Wlin, blin, ws);
    hipLaunchKernelGGL(lstm_kernel, dim3(NBLK), dim3(512), 0, stream, x, ws, out);
}